// Round 7
// baseline (147.157 us; speedup 1.0000x reference)
//
#include <hip/hip_runtime.h>
#include <math.h>

#define RES 96
#define NV 97
#define NV2 (NV * NV)                      // 9409
#define NCELLS (RES * RES * RES)           // 884736
#define NBLK 3456                          // 24*24*6 tiles of 4x4x16
#define MAX_DISP (2.0f / 96.0f / 4.0f)
#define NVT 425                            // 5*5*17 tile vertices

typedef float f32x4 __attribute__((ext_vector_type(4)));

__device__ __forceinline__ float grid_coord(int a) {
    // linspace(-0.5,0.5,97)[a] * 2  ==  a/48 - 1
    return fmaf((float)a, 1.0f / 48.0f, -1.0f);
}

__device__ __forceinline__ float fast_tanh(float x) {
    x = fminf(fmaxf(x, -15.f), 15.f);
    const float e = __expf(2.f * x);
    return (e - 1.f) * __builtin_amdgcn_rcpf(e + 1.f);
}

// One block = 4x4x16 cell tile. Vertices (pos+sdf) and weight rows staged in
// LDS. Grid reduction fused via pure device-scope atomics (NO __threadfence —
// a device fence on CDNA triggers an L2 writeback; 3456 of them serialized the
// whole chip in the previous round: 133us vs 36us).
__global__ __launch_bounds__(256) void flexi_fused(
    const float* __restrict__ sdf,
    const float* __restrict__ deform,
    const float* __restrict__ weights,
    float* __restrict__ out_vd,
    float* __restrict__ acc,          // acc[0]=num, acc[1]=cnt
    unsigned* __restrict__ ticket,
    float* __restrict__ reg_out)
{
    __shared__ float  wlds[16 * 336];      // 16 k-runs x 336 floats
    __shared__ float4 vs4[NVT];            // (x,y,z,sdf) per tile vertex
    __shared__ float  sm[8];
    __shared__ int    lastFlag;

    const int t = threadIdx.x;
    // chunked XCD swizzle: 8 XCDs x 432 contiguous tiles (bijective: 3456=8*432)
    const int bidx = (blockIdx.x & 7) * 432 + (blockIdx.x >> 3);
    const int bi = bidx / 144;             // i-tile (0..23)
    const int rb = bidx - bi * 144;
    const int bj = rb / 6;                 // j-tile (0..23)
    const int bk = rb - bj * 6;            // k-tile (0..5)

    // ---- stage weights: 16 segments of 336 contiguous, 16B-aligned floats ----
    {
        const f32x4* w4 = reinterpret_cast<const f32x4*>(weights);
        #pragma unroll
        for (int it = 0; it < 6; ++it) {
            const int u = t + it * 256;
            if (u < 16 * 84) {
                const int s = u / 84;
                const int q = u - s * 84;
                const int cs = (4 * bi + (s >> 2)) * 9216 + (4 * bj + (s & 3)) * 96 + 16 * bk;
                const f32x4 v = __builtin_nontemporal_load(&w4[(size_t)(cs >> 2) * 21 + q]);
                float* dst = &wlds[s * 336 + q * 4];
                dst[0] = v.x; dst[1] = v.y; dst[2] = v.z; dst[3] = v.w;
            }
        }
    }

    // ---- stage tile vertices: (deformed pos, sdf) as float4 ----
    #pragma unroll
    for (int it = 0; it < 2; ++it) {
        const int u = t + it * 256;
        if (u < NVT) {
            const int a  = u / 85;             // 0..4
            const int r  = u - a * 85;
            const int b  = r / 17;             // 0..4
            const int cc = r - b * 17;         // 0..16
            const int gv = (4 * bi + a) * NV2 + (4 * bj + b) * NV + 16 * bk + cc;
            const float* dp = deform + (size_t)gv * 3;
            float4 vv;
            vv.x = grid_coord(4 * bi + a)   + MAX_DISP * fast_tanh(dp[0]);
            vv.y = grid_coord(4 * bj + b)   + MAX_DISP * fast_tanh(dp[1]);
            vv.z = grid_coord(16 * bk + cc) + MAX_DISP * fast_tanh(dp[2]);
            vv.w = sdf[gv];
            vs4[u] = vv;
        }
    }
    __syncthreads();

    // ---- per-cell compute ----
    const int ti = t >> 6;
    const int tj = (t >> 4) & 3;
    const int tk = t & 15;
    const int vbase = ti * 85 + tj * 17 + tk;
    const int OFF[8] = {0, 85, 17, 102, 1, 86, 18, 103};   // reference corner order

    float s[8], x[8][3];
    #pragma unroll
    for (int k = 0; k < 8; ++k) {
        const float4 vv = vs4[vbase + OFF[k]];
        x[k][0] = vv.x; x[k][1] = vv.y; x[k][2] = vv.z;
        s[k] = vv.w;
    }

    const float* wrow = &wlds[t * 21];     // stride 21: bank-permutation, conflict-free
    float beta[12], alpha[8];
    #pragma unroll
    for (int e = 0; e < 12; ++e) beta[e] = wrow[e];
    #pragma unroll
    for (int k = 0; k < 8; ++k) alpha[k] = wrow[12 + k];
    const float gamma = wrow[20];

    const int EA[12] = {0, 1, 4, 0, 2, 3, 6, 2, 2, 3, 7, 6};
    const int EB[12] = {1, 5, 5, 4, 3, 7, 7, 6, 0, 1, 5, 4};

    float p[12][3];
    bool  cross[12];
    float wsum = 0.f, vnum0 = 0.f, vnum1 = 0.f, vnum2 = 0.f;
    int   ncross = 0;
    #pragma unroll
    for (int e = 0; e < 12; ++e) {
        const int a = EA[e], b = EB[e];
        const float sa = s[a], sb = s[b];
        const bool cr = (sa > 0.f) != (sb > 0.f);
        cross[e] = cr;
        const float ta = alpha[a] * sb;
        const float tb = alpha[b] * sa;
        const float den = cr ? (ta - tb) : 1.0f;
        const float inv = __builtin_amdgcn_rcpf(den);
        float p0 = (ta * x[a][0] - tb * x[b][0]) * inv;
        float p1 = (ta * x[a][1] - tb * x[b][1]) * inv;
        float p2 = (ta * x[a][2] - tb * x[b][2]) * inv;
        p0 = cr ? p0 : 0.f;
        p1 = cr ? p1 : 0.f;
        p2 = cr ? p2 : 0.f;
        p[e][0] = p0; p[e][1] = p1; p[e][2] = p2;
        const float w = cr ? beta[e] : 0.f;
        wsum  += w;
        vnum0 += w * p0;
        vnum1 += w * p1;
        vnum2 += w * p2;
        ncross += cr ? 1 : 0;
    }

    const bool surf = (ncross > 0);
    const float invden = __builtin_amdgcn_rcpf(surf ? wsum : 1.0f);
    float vd0 = vnum0 * invden;
    float vd1 = vnum1 * invden;
    float vd2 = vnum2 * invden;
    if (!surf) { vd0 = 0.f; vd1 = 0.f; vd2 = 0.f; }

    const int c = (4 * bi + ti) * 9216 + (4 * bj + tj) * 96 + 16 * bk + tk;
    out_vd[(size_t)c * 3 + 0] = vd0;
    out_vd[(size_t)c * 3 + 1] = vd1;
    out_vd[(size_t)c * 3 + 2] = vd2;

    float devsum = 0.f;
    #pragma unroll
    for (int e = 0; e < 12; ++e) {
        const float d0 = p[e][0] - vd0;
        const float d1 = p[e][1] - vd1;
        const float d2 = p[e][2] - vd2;
        const float nrm = __builtin_amdgcn_sqrtf(d0 * d0 + d1 * d1 + d2 * d2 + 1e-12f);
        devsum += cross[e] ? nrm : 0.f;
    }
    const float dev = devsum * __builtin_amdgcn_rcpf(fmaxf((float)ncross, 1.0f));
    float regc = surf ? dev * gamma : 0.f;
    float cnt  = surf ? 1.0f : 0.f;

    #pragma unroll
    for (int off = 32; off > 0; off >>= 1) {
        regc += __shfl_down(regc, off);
        cnt  += __shfl_down(cnt, off);
    }
    const int wid = t >> 6;
    if ((t & 63) == 0) { sm[wid] = regc; sm[4 + wid] = cnt; }
    __syncthreads();
    if (t == 0) {
        const float bnum = sm[0] + sm[1] + sm[2] + sm[3];
        const float bcnt = sm[4] + sm[5] + sm[6] + sm[7];
        // device-scope atomics: coherent at L2 coherence point, no cache flush
        const float r0 = atomicAdd(&acc[0], bnum);
        const float r1 = atomicAdd(&acc[1], bcnt);
        // consume returns -> compiler emits s_waitcnt vmcnt before the asm,
        // guaranteeing both adds completed before the ticket increments
        asm volatile("" :: "v"(r0), "v"(r1));
        const unsigned old = atomicAdd(ticket, 1u);
        lastFlag = (old == NBLK - 1);
    }
    __syncthreads();

    // ---- last block finalizes reg (atomic reads are coherent, no fence) ----
    if (lastFlag && t == 0) {
        const float num = atomicAdd(&acc[0], 0.0f);
        const float den = atomicAdd(&acc[1], 0.0f);
        reg_out[0] = num / fmaxf(den, 1.0f);
    }
}

extern "C" void kernel_launch(void* const* d_in, const int* in_sizes, int n_in,
                              void* d_out, int out_size, void* d_ws, size_t ws_size,
                              hipStream_t stream)
{
    // inputs: verts(analytic), indices(analytic), sdf, deform, weights
    const float* sdf     = (const float*)d_in[2];
    const float* deform  = (const float*)d_in[3];
    const float* weights = (const float*)d_in[4];
    float* out      = (float*)d_out;
    float* acc      = (float*)d_ws;                    // [num, cnt]
    unsigned* ticket = (unsigned*)((char*)d_ws + 2 * sizeof(float));

    (void)hipMemsetAsync(d_ws, 0, 3 * sizeof(float), stream);
    flexi_fused<<<NBLK, 256, 0, stream>>>(sdf, deform, weights, out, acc,
                                          ticket, out + (size_t)NCELLS * 3);
}

// Round 8
// 35.682 us; speedup vs baseline: 4.1241x; 4.1241x over previous
//
#include <hip/hip_runtime.h>
#include <math.h>

#define RES 96
#define NV 97
#define NV2 (NV * NV)                      // 9409
#define NCELLS (RES * RES * RES)           // 884736
#define NBLK 3456                          // 24*24*6 tiles of 4x4x16
#define MAX_DISP (2.0f / 96.0f / 4.0f)
#define NVT 425                            // 5*5*17 tile vertices

typedef float f32x4 __attribute__((ext_vector_type(4)));

__device__ __forceinline__ float grid_coord(int a) {
    // linspace(-0.5,0.5,97)[a] * 2  ==  a/48 - 1
    return fmaf((float)a, 1.0f / 48.0f, -1.0f);
}

__device__ __forceinline__ float fast_tanh(float x) {
    x = fminf(fmaxf(x, -15.f), 15.f);
    const float e = __expf(2.f * x);
    return (e - 1.f) * __builtin_amdgcn_rcpf(e + 1.f);
}

// One block = 4x4x16 cell tile. Vertices (pos+sdf float4) and weight rows in
// LDS. Per-block reg partials go to DISTINCT addresses; a tiny second kernel
// reduces them. (Fused same-address atomic reductions serialized at the
// device coherence point and cost ~110us in R6/R7 — never again.)
__global__ __launch_bounds__(256) void flexi_fused(
    const float* __restrict__ sdf,
    const float* __restrict__ deform,
    const float* __restrict__ weights,
    float* __restrict__ out_vd,
    float* __restrict__ partial)
{
    __shared__ float  wlds[16 * 336];      // 16 k-runs x 336 floats
    __shared__ float4 vs4[NVT];            // (x,y,z,sdf) per tile vertex
    __shared__ float  sm[8];

    const int t = threadIdx.x;
    // chunked XCD swizzle: 8 XCDs x 432 contiguous tiles (bijective: 3456=8*432)
    const int bidx = (blockIdx.x & 7) * 432 + (blockIdx.x >> 3);
    const int bi = bidx / 144;             // i-tile (0..23)
    const int rb = bidx - bi * 144;
    const int bj = rb / 6;                 // j-tile (0..23)
    const int bk = rb - bj * 6;            // k-tile (0..5)

    // ---- stage weights: 16 segments of 336 contiguous, 16B-aligned floats ----
    {
        const f32x4* w4 = reinterpret_cast<const f32x4*>(weights);
        #pragma unroll
        for (int it = 0; it < 6; ++it) {
            const int u = t + it * 256;
            if (u < 16 * 84) {
                const int s = u / 84;
                const int q = u - s * 84;
                const int cs = (4 * bi + (s >> 2)) * 9216 + (4 * bj + (s & 3)) * 96 + 16 * bk;
                const f32x4 v = __builtin_nontemporal_load(&w4[(size_t)(cs >> 2) * 21 + q]);
                float* dst = &wlds[s * 336 + q * 4];
                dst[0] = v.x; dst[1] = v.y; dst[2] = v.z; dst[3] = v.w;
            }
        }
    }

    // ---- stage tile vertices: (deformed pos, sdf) as float4 ----
    #pragma unroll
    for (int it = 0; it < 2; ++it) {
        const int u = t + it * 256;
        if (u < NVT) {
            const int a  = u / 85;             // 0..4
            const int r  = u - a * 85;
            const int b  = r / 17;             // 0..4
            const int cc = r - b * 17;         // 0..16
            const int gv = (4 * bi + a) * NV2 + (4 * bj + b) * NV + 16 * bk + cc;
            const float* dp = deform + (size_t)gv * 3;
            float4 vv;
            vv.x = grid_coord(4 * bi + a)   + MAX_DISP * fast_tanh(dp[0]);
            vv.y = grid_coord(4 * bj + b)   + MAX_DISP * fast_tanh(dp[1]);
            vv.z = grid_coord(16 * bk + cc) + MAX_DISP * fast_tanh(dp[2]);
            vv.w = sdf[gv];
            vs4[u] = vv;
        }
    }
    __syncthreads();

    // ---- per-cell compute ----
    const int ti = t >> 6;
    const int tj = (t >> 4) & 3;
    const int tk = t & 15;
    const int vbase = ti * 85 + tj * 17 + tk;
    const int OFF[8] = {0, 85, 17, 102, 1, 86, 18, 103};   // reference corner order

    float s[8], x[8][3];
    #pragma unroll
    for (int k = 0; k < 8; ++k) {
        const float4 vv = vs4[vbase + OFF[k]];
        x[k][0] = vv.x; x[k][1] = vv.y; x[k][2] = vv.z;
        s[k] = vv.w;
    }

    const float* wrow = &wlds[t * 21];     // stride 21: odd -> conflict-free
    float beta[12], alpha[8];
    #pragma unroll
    for (int e = 0; e < 12; ++e) beta[e] = wrow[e];
    #pragma unroll
    for (int k = 0; k < 8; ++k) alpha[k] = wrow[12 + k];
    const float gamma = wrow[20];

    const int EA[12] = {0, 1, 4, 0, 2, 3, 6, 2, 2, 3, 7, 6};
    const int EB[12] = {1, 5, 5, 4, 3, 7, 7, 6, 0, 1, 5, 4};

    float p[12][3];
    bool  cross[12];
    float wsum = 0.f, vnum0 = 0.f, vnum1 = 0.f, vnum2 = 0.f;
    int   ncross = 0;
    #pragma unroll
    for (int e = 0; e < 12; ++e) {
        const int a = EA[e], b = EB[e];
        const float sa = s[a], sb = s[b];
        const bool cr = (sa > 0.f) != (sb > 0.f);
        cross[e] = cr;
        const float ta = alpha[a] * sb;
        const float tb = alpha[b] * sa;
        const float den = cr ? (ta - tb) : 1.0f;
        const float inv = __builtin_amdgcn_rcpf(den);
        float p0 = (ta * x[a][0] - tb * x[b][0]) * inv;
        float p1 = (ta * x[a][1] - tb * x[b][1]) * inv;
        float p2 = (ta * x[a][2] - tb * x[b][2]) * inv;
        p0 = cr ? p0 : 0.f;
        p1 = cr ? p1 : 0.f;
        p2 = cr ? p2 : 0.f;
        p[e][0] = p0; p[e][1] = p1; p[e][2] = p2;
        const float w = cr ? beta[e] : 0.f;
        wsum  += w;
        vnum0 += w * p0;
        vnum1 += w * p1;
        vnum2 += w * p2;
        ncross += cr ? 1 : 0;
    }

    const bool surf = (ncross > 0);
    const float invden = __builtin_amdgcn_rcpf(surf ? wsum : 1.0f);
    float vd0 = vnum0 * invden;
    float vd1 = vnum1 * invden;
    float vd2 = vnum2 * invden;
    if (!surf) { vd0 = 0.f; vd1 = 0.f; vd2 = 0.f; }

    const int c = (4 * bi + ti) * 9216 + (4 * bj + tj) * 96 + 16 * bk + tk;
    out_vd[(size_t)c * 3 + 0] = vd0;
    out_vd[(size_t)c * 3 + 1] = vd1;
    out_vd[(size_t)c * 3 + 2] = vd2;

    float devsum = 0.f;
    #pragma unroll
    for (int e = 0; e < 12; ++e) {
        const float d0 = p[e][0] - vd0;
        const float d1 = p[e][1] - vd1;
        const float d2 = p[e][2] - vd2;
        const float nrm = __builtin_amdgcn_sqrtf(d0 * d0 + d1 * d1 + d2 * d2 + 1e-12f);
        devsum += cross[e] ? nrm : 0.f;
    }
    const float dev = devsum * __builtin_amdgcn_rcpf(fmaxf((float)ncross, 1.0f));
    float regc = surf ? dev * gamma : 0.f;
    float cnt  = surf ? 1.0f : 0.f;

    #pragma unroll
    for (int off = 32; off > 0; off >>= 1) {
        regc += __shfl_down(regc, off);
        cnt  += __shfl_down(cnt, off);
    }
    const int wid = t >> 6;
    if ((t & 63) == 0) { sm[wid] = regc; sm[4 + wid] = cnt; }
    __syncthreads();
    if (t == 0) {
        partial[bidx]        = sm[0] + sm[1] + sm[2] + sm[3];
        partial[NBLK + bidx] = sm[4] + sm[5] + sm[6] + sm[7];
    }
}

__global__ __launch_bounds__(256) void flexi_reduce(
    const float* __restrict__ partial, float* __restrict__ reg_out)
{
    float a = 0.f, b = 0.f;
    for (int i = threadIdx.x; i < NBLK; i += 256) {
        a += partial[i];
        b += partial[NBLK + i];
    }
    #pragma unroll
    for (int off = 32; off > 0; off >>= 1) {
        a += __shfl_down(a, off);
        b += __shfl_down(b, off);
    }
    __shared__ float sm[8];
    const int wid = threadIdx.x >> 6;
    if ((threadIdx.x & 63) == 0) { sm[wid] = a; sm[4 + wid] = b; }
    __syncthreads();
    if (threadIdx.x == 0) {
        const float num = sm[0] + sm[1] + sm[2] + sm[3];
        const float den = sm[4] + sm[5] + sm[6] + sm[7];
        reg_out[0] = num / fmaxf(den, 1.0f);
    }
}

extern "C" void kernel_launch(void* const* d_in, const int* in_sizes, int n_in,
                              void* d_out, int out_size, void* d_ws, size_t ws_size,
                              hipStream_t stream)
{
    // inputs: verts(analytic), indices(analytic), sdf, deform, weights
    const float* sdf     = (const float*)d_in[2];
    const float* deform  = (const float*)d_in[3];
    const float* weights = (const float*)d_in[4];
    float* out     = (float*)d_out;
    float* partial = (float*)d_ws;     // 2*NBLK floats, all rewritten each call

    flexi_fused<<<NBLK, 256, 0, stream>>>(sdf, deform, weights, out, partial);
    flexi_reduce<<<1, 256, 0, stream>>>(partial, out + (size_t)NCELLS * 3);
}

// Round 9
// 35.095 us; speedup vs baseline: 4.1930x; 1.0167x over previous
//
#include <hip/hip_runtime.h>
#include <math.h>

#define RES 96
#define NV 97
#define NV2 (NV * NV)                      // 9409
#define NCELLS (RES * RES * RES)           // 884736
#define NBLK 3456                          // 24*24*6 tiles of 4x4x16
#define MAX_DISP (2.0f / 96.0f / 4.0f)
#define NVT 425                            // 5*5*17 tile vertices

typedef float f32x4 __attribute__((ext_vector_type(4)));

__device__ __forceinline__ float grid_coord(int a) {
    // linspace(-0.5,0.5,97)[a] * 2  ==  a/48 - 1
    return fmaf((float)a, 1.0f / 48.0f, -1.0f);
}

__device__ __forceinline__ float fast_tanh(float x) {
    x = fminf(fmaxf(x, -15.f), 15.f);
    const float e = __expf(2.f * x);
    return (e - 1.f) * __builtin_amdgcn_rcpf(e + 1.f);
}

// One block = 4x4x16 cell tile. Vertices (pos+sdf float4) and weight rows in
// LDS. launch_bounds(256,3): default heuristic allocated only 48 VGPRs and
// spilled the ~90-float working set into LDS re-reads/AGPR shuttles (R6/R7
// counters); 3 blocks/CU gives ~170 VGPR budget which holds it all.
// Per-block reg partials to DISTINCT addresses + tiny reduce kernel (fused
// same-address atomics serialized at the coherence point: 4x regression).
__global__ __launch_bounds__(256, 3) void flexi_fused(
    const float* __restrict__ sdf,
    const float* __restrict__ deform,
    const float* __restrict__ weights,
    float* __restrict__ out_vd,
    float* __restrict__ partial)
{
    __shared__ float  wlds[16 * 336];      // 16 k-runs x 336 floats
    __shared__ float4 vs4[NVT];            // (x,y,z,sdf) per tile vertex
    __shared__ float  sm[8];

    const int t = threadIdx.x;
    // chunked XCD swizzle: 8 XCDs x 432 contiguous tiles (bijective: 3456=8*432)
    const int bidx = (blockIdx.x & 7) * 432 + (blockIdx.x >> 3);
    const int bi = bidx / 144;             // i-tile (0..23)
    const int rb = bidx - bi * 144;
    const int bj = rb / 6;                 // j-tile (0..23)
    const int bk = rb - bj * 6;            // k-tile (0..5)

    // ---- stage weights: 16 segments of 336 contiguous, 16B-aligned floats ----
    {
        const f32x4* w4 = reinterpret_cast<const f32x4*>(weights);
        #pragma unroll
        for (int it = 0; it < 6; ++it) {
            const int u = t + it * 256;
            if (u < 16 * 84) {
                const int s = u / 84;
                const int q = u - s * 84;
                const int cs = (4 * bi + (s >> 2)) * 9216 + (4 * bj + (s & 3)) * 96 + 16 * bk;
                const f32x4 v = __builtin_nontemporal_load(&w4[(size_t)(cs >> 2) * 21 + q]);
                float* dst = &wlds[s * 336 + q * 4];
                dst[0] = v.x; dst[1] = v.y; dst[2] = v.z; dst[3] = v.w;
            }
        }
    }

    // ---- stage tile vertices: (deformed pos, sdf) as float4 ----
    #pragma unroll
    for (int it = 0; it < 2; ++it) {
        const int u = t + it * 256;
        if (u < NVT) {
            const int a  = u / 85;             // 0..4
            const int r  = u - a * 85;
            const int b  = r / 17;             // 0..4
            const int cc = r - b * 17;         // 0..16
            const int gv = (4 * bi + a) * NV2 + (4 * bj + b) * NV + 16 * bk + cc;
            const float* dp = deform + (size_t)gv * 3;
            float4 vv;
            vv.x = grid_coord(4 * bi + a)   + MAX_DISP * fast_tanh(dp[0]);
            vv.y = grid_coord(4 * bj + b)   + MAX_DISP * fast_tanh(dp[1]);
            vv.z = grid_coord(16 * bk + cc) + MAX_DISP * fast_tanh(dp[2]);
            vv.w = sdf[gv];
            vs4[u] = vv;
        }
    }
    __syncthreads();

    // ---- per-cell compute ----
    const int ti = t >> 6;
    const int tj = (t >> 4) & 3;
    const int tk = t & 15;
    const int vbase = ti * 85 + tj * 17 + tk;
    const int OFF[8] = {0, 85, 17, 102, 1, 86, 18, 103};   // reference corner order

    float s[8], x[8][3];
    #pragma unroll
    for (int k = 0; k < 8; ++k) {
        const float4 vv = vs4[vbase + OFF[k]];
        x[k][0] = vv.x; x[k][1] = vv.y; x[k][2] = vv.z;
        s[k] = vv.w;
    }

    const float* wrow = &wlds[t * 21];     // stride 21: odd -> conflict-free
    float beta[12], alpha[8];
    #pragma unroll
    for (int e = 0; e < 12; ++e) beta[e] = wrow[e];
    #pragma unroll
    for (int k = 0; k < 8; ++k) alpha[k] = wrow[12 + k];
    const float gamma = wrow[20];

    const int EA[12] = {0, 1, 4, 0, 2, 3, 6, 2, 2, 3, 7, 6};
    const int EB[12] = {1, 5, 5, 4, 3, 7, 7, 6, 0, 1, 5, 4};

    float p[12][3];
    bool  cross[12];
    float wsum = 0.f, vnum0 = 0.f, vnum1 = 0.f, vnum2 = 0.f;
    int   ncross = 0;
    #pragma unroll
    for (int e = 0; e < 12; ++e) {
        const int a = EA[e], b = EB[e];
        const float sa = s[a], sb = s[b];
        const bool cr = (sa > 0.f) != (sb > 0.f);
        cross[e] = cr;
        const float ta = alpha[a] * sb;
        const float tb = alpha[b] * sa;
        // den guard keeps p finite (w=0 masks its value, but 0*inf = NaN)
        const float den = cr ? (ta - tb) : 1.0f;
        const float inv = __builtin_amdgcn_rcpf(den);
        // no p-zeroing: non-crossing edges contribute w=0 -> 0*finite = 0,
        // and the dev loop masks nrm with `cross[e]` -> identical semantics
        const float p0 = (ta * x[a][0] - tb * x[b][0]) * inv;
        const float p1 = (ta * x[a][1] - tb * x[b][1]) * inv;
        const float p2 = (ta * x[a][2] - tb * x[b][2]) * inv;
        p[e][0] = p0; p[e][1] = p1; p[e][2] = p2;
        const float w = cr ? beta[e] : 0.f;
        wsum  += w;
        vnum0 += w * p0;
        vnum1 += w * p1;
        vnum2 += w * p2;
        ncross += cr ? 1 : 0;
    }

    const bool surf = (ncross > 0);
    const float invden = __builtin_amdgcn_rcpf(surf ? wsum : 1.0f);
    float vd0 = vnum0 * invden;
    float vd1 = vnum1 * invden;
    float vd2 = vnum2 * invden;
    if (!surf) { vd0 = 0.f; vd1 = 0.f; vd2 = 0.f; }

    const int c = (4 * bi + ti) * 9216 + (4 * bj + tj) * 96 + 16 * bk + tk;
    out_vd[(size_t)c * 3 + 0] = vd0;
    out_vd[(size_t)c * 3 + 1] = vd1;
    out_vd[(size_t)c * 3 + 2] = vd2;

    float devsum = 0.f;
    #pragma unroll
    for (int e = 0; e < 12; ++e) {
        const float d0 = p[e][0] - vd0;
        const float d1 = p[e][1] - vd1;
        const float d2 = p[e][2] - vd2;
        const float nrm = __builtin_amdgcn_sqrtf(d0 * d0 + d1 * d1 + d2 * d2 + 1e-12f);
        devsum += cross[e] ? nrm : 0.f;
    }
    const float dev = devsum * __builtin_amdgcn_rcpf(fmaxf((float)ncross, 1.0f));
    float regc = surf ? dev * gamma : 0.f;
    float cnt  = surf ? 1.0f : 0.f;

    #pragma unroll
    for (int off = 32; off > 0; off >>= 1) {
        regc += __shfl_down(regc, off);
        cnt  += __shfl_down(cnt, off);
    }
    const int wid = t >> 6;
    if ((t & 63) == 0) { sm[wid] = regc; sm[4 + wid] = cnt; }
    __syncthreads();
    if (t == 0) {
        partial[bidx]        = sm[0] + sm[1] + sm[2] + sm[3];
        partial[NBLK + bidx] = sm[4] + sm[5] + sm[6] + sm[7];
    }
}

__global__ __launch_bounds__(256) void flexi_reduce(
    const float* __restrict__ partial, float* __restrict__ reg_out)
{
    float a = 0.f, b = 0.f;
    for (int i = threadIdx.x; i < NBLK; i += 256) {
        a += partial[i];
        b += partial[NBLK + i];
    }
    #pragma unroll
    for (int off = 32; off > 0; off >>= 1) {
        a += __shfl_down(a, off);
        b += __shfl_down(b, off);
    }
    __shared__ float sm[8];
    const int wid = threadIdx.x >> 6;
    if ((threadIdx.x & 63) == 0) { sm[wid] = a; sm[4 + wid] = b; }
    __syncthreads();
    if (threadIdx.x == 0) {
        const float num = sm[0] + sm[1] + sm[2] + sm[3];
        const float den = sm[4] + sm[5] + sm[6] + sm[7];
        reg_out[0] = num / fmaxf(den, 1.0f);
    }
}

extern "C" void kernel_launch(void* const* d_in, const int* in_sizes, int n_in,
                              void* d_out, int out_size, void* d_ws, size_t ws_size,
                              hipStream_t stream)
{
    // inputs: verts(analytic), indices(analytic), sdf, deform, weights
    const float* sdf     = (const float*)d_in[2];
    const float* deform  = (const float*)d_in[3];
    const float* weights = (const float*)d_in[4];
    float* out     = (float*)d_out;
    float* partial = (float*)d_ws;     // 2*NBLK floats, all rewritten each call

    flexi_fused<<<NBLK, 256, 0, stream>>>(sdf, deform, weights, out, partial);
    flexi_reduce<<<1, 256, 0, stream>>>(partial, out + (size_t)NCELLS * 3);
}